// Round 15
// baseline (129.122 us; speedup 1.0000x reference)
//
#include <hip/hip_runtime.h>

#define NB 8192
#define ND 256
#define NCLS 64
#define LOSS_MARGIN 0.2f
#define NEG_INF_F (-1e9f)
#define NBLK_LOSS 256   // 64 classes x 4 row-chunks
#define NT 64           // 8192/128 tile grid
#define NTILE_T 2080    // 64*65/2 triangular tiles

typedef __attribute__((ext_vector_type(8))) __bf16 bf16x8;
typedef __attribute__((ext_vector_type(4))) float f32x4;

// fp32 -> bf16 bits, round-to-nearest-even
__device__ __forceinline__ unsigned short f2bf(float f) {
  unsigned u = __float_as_uint(f);
  unsigned r = (u + 0x7fffu + ((u >> 16) & 1u)) >> 16;
  return (unsigned short)r;
}

// async global->LDS, 16 bytes per lane
__device__ __forceinline__ void gl_lds16(const void* gsrc, void* ldst) {
  __builtin_amdgcn_global_load_lds(
      (const __attribute__((address_space(1))) void*)gsrc,
      (__attribute__((address_space(3))) void*)ldst, 16, 0, 0);
}

// ---- class_start + stable class index list; 2 barriers total ----
__global__ __launch_bounds__(256) void build_idx(const int* __restrict__ aff,
                                                 int* __restrict__ class_start,
                                                 int* __restrict__ class_idx) {
  const int c = blockIdx.x;
  const int t = threadIdx.x;
  const int lane = t & 63, wave = t >> 6;
  __shared__ int wtotLT[4];
  __shared__ int wtotEQ[4];

  int a[32];
#pragma unroll
  for (int k = 0; k < 32; ++k) a[k] = aff[t * 32 + k];
  int ltc = 0, meq = 0;
#pragma unroll
  for (int k = 0; k < 32; ++k) {
    ltc += (a[k] < c) ? 1 : 0;
    meq += (a[k] == c) ? 1 : 0;
  }

  int sc = meq;
  for (int d = 1; d < 64; d <<= 1) {
    int n = __shfl_up(sc, d);
    if (lane >= d) sc += n;
  }
  int ltr = ltc;
  for (int off = 32; off; off >>= 1) ltr += __shfl_down(ltr, off);
  if (lane == 63) wtotEQ[wave] = sc;
  if (lane == 0) wtotLT[wave] = ltr;
  __syncthreads();

  int base = wtotLT[0] + wtotLT[1] + wtotLT[2] + wtotLT[3];
  int wpre = 0;
  for (int w = 0; w < wave; ++w) wpre += wtotEQ[w];
  int p = base + wpre + (sc - meq);

  if (t == 0) {
    class_start[c] = base;
    if (c == 0) class_start[NCLS] = NB;
  }
#pragma unroll
  for (int k = 0; k < 32; ++k)
    if (a[k] == c) class_idx[p++] = t * 32 + k;
}

// ---- gather rows in class order, convert to bf16 (grid-wide parallel) ----
__global__ __launch_bounds__(256) void gather_convert(const float* __restrict__ P,
                                                      const int* __restrict__ aff,
                                                      const int* __restrict__ inst,
                                                      const int* __restrict__ class_idx,
                                                      unsigned short* __restrict__ Psort,
                                                      int* __restrict__ affSort,
                                                      int* __restrict__ instSort) {
  const int t = threadIdx.x;
  const int sr = blockIdx.x * 8 + (t >> 5);
  const int c = t & 31;
  const int src = class_idx[sr];
  const float4* ps = (const float4*)(P + (size_t)src * ND);
  ushort4* pd = (ushort4*)(Psort + (size_t)sr * ND);
#pragma unroll
  for (int q = 0; q < 2; ++q) {
    float4 v = ps[c + q * 32];
    ushort4 h;
    h.x = f2bf(v.x); h.y = f2bf(v.y); h.z = f2bf(v.z); h.w = f2bf(v.w);
    pd[c + q * 32] = h;
  }
  if (c == 0) {
    affSort[sr] = aff[src];
    instSort[sr] = inst[src];
  }
}

// ---- MFMA simmax: R13-exact K-loop; masked tiles also store sims (bf16) ----
// part layout: [tileCol][row]; simbuf slot = bi*4 + (bj-bi), 128x128 bf16.
__global__ __launch_bounds__(256, 4) void simmax_mfma(const unsigned short* __restrict__ Psort,
                                                      const int* __restrict__ affSort,
                                                      float* __restrict__ part,
                                                      unsigned short* __restrict__ simbuf) {
  int wg = blockIdx.x;
  wg = (wg & 7) * (NTILE_T / 8) + (wg >> 3);
  int bi = (int)((129.0f - sqrtf(129.0f * 129.0f - 8.0f * (float)wg)) * 0.5f);
  while (bi * 64 - bi * (bi - 1) / 2 > wg) --bi;
  while ((bi + 1) * 64 - (bi + 1) * bi / 2 <= wg) ++bi;
  const int bj = bi + (wg - (bi * 64 - bi * (bi - 1) / 2));

  __shared__ __align__(16) unsigned short smemu[16384];
  float* rowmax_s = (float*)&smemu[0];     // [128][2], overlays buffer 0 A
  float* colmax_s = (float*)&smemu[512];   // [128][2]

  const int t = threadIdx.x;
  const int lane = t & 63;
  const int wave = t >> 6;
  const int r0 = bi * 128, c0 = bj * 128;

  const bool needMask = (affSort[c0] <= affSort[r0 + 127]);

  const int wr = (wave >> 1) * 64;
  const int wc = (wave & 1) * 64;

  f32x4 acc[4][4];
#pragma unroll
  for (int m = 0; m < 4; ++m)
#pragma unroll
    for (int n = 0; n < 4; ++n) acc[m][n] = (f32x4){0.f, 0.f, 0.f, 0.f};

  const int ci0 = t, ci1 = 256 + t;
  const int kg0 = ci0 >> 7, rw0 = ci0 & 127;
  const int kg1 = ci1 >> 7, rw1 = ci1 & 127;

#define STAGE_SIM(B, KC)                                                      \
  do {                                                                        \
    gl_lds16(Psort + (size_t)(r0 + rw0) * ND + (KC) + kg0 * 8,                \
             &smemu[(B) * 4096 + ci0 * 8]);                                   \
    gl_lds16(Psort + (size_t)(c0 + rw0) * ND + (KC) + kg0 * 8,                \
             &smemu[8192 + (B) * 4096 + ci0 * 8]);                            \
    gl_lds16(Psort + (size_t)(r0 + rw1) * ND + (KC) + kg1 * 8,                \
             &smemu[(B) * 4096 + ci1 * 8]);                                   \
    gl_lds16(Psort + (size_t)(c0 + rw1) * ND + (KC) + kg1 * 8,                \
             &smemu[8192 + (B) * 4096 + ci1 * 8]);                            \
  } while (0)

  STAGE_SIM(0, 0);
  asm volatile("s_waitcnt vmcnt(0) lgkmcnt(0)" ::: "memory");
  __builtin_amdgcn_s_barrier();
  __builtin_amdgcn_sched_barrier(0);

  int cur = 0;
#pragma unroll 1
  for (int s = 0; s < 8; ++s) {
    if (s < 7) STAGE_SIM(cur ^ 1, (s + 1) * 32);
    const int kg = lane >> 4, lr = lane & 15;
    bf16x8 a[4], b[4];
#pragma unroll
    for (int m = 0; m < 4; ++m)
      a[m] = *(const bf16x8*)&smemu[cur * 4096 + (kg * 128 + wr + m * 16 + lr) * 8];
#pragma unroll
    for (int n = 0; n < 4; ++n)
      b[n] = *(const bf16x8*)&smemu[8192 + cur * 4096 + (kg * 128 + wc + n * 16 + lr) * 8];
#pragma unroll
    for (int m = 0; m < 4; ++m)
#pragma unroll
      for (int n = 0; n < 4; ++n)
        acc[m][n] = __builtin_amdgcn_mfma_f32_16x16x32_bf16(a[m], b[n], acc[m][n], 0, 0, 0);
    __builtin_amdgcn_sched_barrier(0);
    if (s < 7) {
      asm volatile("s_waitcnt vmcnt(0)" ::: "memory");
      __builtin_amdgcn_s_barrier();
      __builtin_amdgcn_sched_barrier(0);
    }
    cur ^= 1;
  }
  // all waves past the s==6 barrier: buffer 0 is dead -> reuse as scratch

  if (needMask) {
    int aj[4];
#pragma unroll
    for (int n = 0; n < 4; ++n) aj[n] = affSort[c0 + wc + n * 16 + (lane & 15)];
#pragma unroll
    for (int m = 0; m < 4; ++m) {
#pragma unroll
      for (int r = 0; r < 4; ++r) {
        const int lrow = wr + m * 16 + (lane >> 4) * 4 + r;
        const int ai = affSort[r0 + lrow];
        float rmax = NEG_INF_F;
#pragma unroll
        for (int n = 0; n < 4; ++n)
          if (aj[n] != ai) rmax = fmaxf(rmax, acc[m][n][r]);
        rmax = fmaxf(rmax, __shfl_xor(rmax, 1));
        rmax = fmaxf(rmax, __shfl_xor(rmax, 2));
        rmax = fmaxf(rmax, __shfl_xor(rmax, 4));
        rmax = fmaxf(rmax, __shfl_xor(rmax, 8));
        if ((lane & 15) == 0) rowmax_s[lrow * 2 + (wc >> 6)] = rmax;
      }
    }
    if (bi != bj) {
#pragma unroll
      for (int n = 0; n < 4; ++n) {
        const int lcol = wc + n * 16 + (lane & 15);
        float cmax = NEG_INF_F;
#pragma unroll
        for (int m = 0; m < 4; ++m) {
          const int lrb = wr + m * 16 + (lane >> 4) * 4;
#pragma unroll
          for (int r = 0; r < 4; ++r)
            if (affSort[r0 + lrb + r] != aj[n]) cmax = fmaxf(cmax, acc[m][n][r]);
        }
        cmax = fmaxf(cmax, __shfl_xor(cmax, 16));
        cmax = fmaxf(cmax, __shfl_xor(cmax, 32));
        if (lane < 16) colmax_s[lcol * 2 + (wr >> 6)] = cmax;
      }
    }
    // store the sim tile (bf16) for the loss pass; slot = bi*4 + (bj-bi) <= 255
    const int d = bj - bi;
    if (d < 4) {
      unsigned short* dst = simbuf + ((size_t)((bi << 2) + d) << 14);
#pragma unroll
      for (int m = 0; m < 4; ++m) {
#pragma unroll
        for (int r = 0; r < 4; ++r) {
          const int lrow = wr + m * 16 + (lane >> 4) * 4 + r;
#pragma unroll
          for (int n = 0; n < 4; ++n) {
            const int lcol = wc + n * 16 + (lane & 15);
            dst[lrow * 128 + lcol] = f2bf(acc[m][n][r]);
          }
        }
      }
    }
  } else {
#pragma unroll
    for (int m = 0; m < 4; ++m) {
#pragma unroll
      for (int r = 0; r < 4; ++r) {
        float rmax = fmaxf(fmaxf(acc[m][0][r], acc[m][1][r]),
                           fmaxf(acc[m][2][r], acc[m][3][r]));
        rmax = fmaxf(rmax, __shfl_xor(rmax, 1));
        rmax = fmaxf(rmax, __shfl_xor(rmax, 2));
        rmax = fmaxf(rmax, __shfl_xor(rmax, 4));
        rmax = fmaxf(rmax, __shfl_xor(rmax, 8));
        if ((lane & 15) == 0)
          rowmax_s[(wr + m * 16 + (lane >> 4) * 4 + r) * 2 + (wc >> 6)] = rmax;
      }
    }
#pragma unroll
    for (int n = 0; n < 4; ++n) {
      float cmax = NEG_INF_F;
#pragma unroll
      for (int m = 0; m < 4; ++m)
#pragma unroll
        for (int r = 0; r < 4; ++r) cmax = fmaxf(cmax, acc[m][n][r]);
      cmax = fmaxf(cmax, __shfl_xor(cmax, 16));
      cmax = fmaxf(cmax, __shfl_xor(cmax, 32));
      if (lane < 16) colmax_s[(wc + n * 16 + (lane & 15)) * 2 + (wr >> 6)] = cmax;
    }
  }
  __syncthreads();
  if (t < 128) {
    part[(size_t)bj * NB + (r0 + t)] = fmaxf(rowmax_s[t * 2], rowmax_s[t * 2 + 1]);
  } else if (bi != bj) {
    const int cc = t - 128;
    part[(size_t)bi * NB + (c0 + cc)] = fmaxf(colmax_s[cc * 2], colmax_s[cc * 2 + 1]);
  }
#undef STAGE_SIM
}

// ---- reduce 64 partial maxima per row -> hn[row] (coalesced col-major) ----
__global__ __launch_bounds__(256) void hn_reduce(const float* __restrict__ part,
                                                 float* __restrict__ hn) {
  const int i = blockIdx.x * 256 + threadIdx.x;
  float m = NEG_INF_F;
#pragma unroll 16
  for (int q = 0; q < NT; ++q) m = fmaxf(m, part[(size_t)q * NB + i]);
  hn[i] = m;
}

// ---- loss over positive pairs via stored sims (no MFMA) ----
// grid: (4 row-chunks, 64 classes). Each ordered pair (ri anchor, rj pos).
__global__ __launch_bounds__(256) void loss_pairs(const int* __restrict__ class_start,
                                                  const int* __restrict__ instSort,
                                                  const float* __restrict__ hn,
                                                  const unsigned short* __restrict__ simbuf,
                                                  float* __restrict__ bsum,
                                                  int* __restrict__ bcnt) {
  const int c = blockIdx.y;
  const int chunk = blockIdx.x;
  const int bid = c * 4 + chunk;
  const int t = threadIdx.x;
  const int lane = t & 63, wave = t >> 6;
  const int base = class_start[c];
  const int cnt = class_start[c + 1] - base;

  float lsum = 0.f;
  int lcnt = 0;

  if (cnt < NB) {
#pragma unroll 1
    for (int ri = chunk; ri < cnt; ri += 4) {
      const int gi = base + ri;
      const float hnv = hn[gi];
      const int ii = instSort[gi];
#pragma unroll 1
      for (int rj = t; rj < cnt; rj += 256) {
        if (rj == ri) continue;
        const int gj = base + rj;
        if (instSort[gj] != ii) {
          const int lo = min(gi, gj), hi = max(gi, gj);
          const int b0 = lo >> 7, d = (hi >> 7) - b0;
          const unsigned short sb =
              simbuf[((size_t)((b0 << 2) + d) << 14) + ((lo & 127) << 7) + (hi & 127)];
          const float s = __uint_as_float((unsigned)sb << 16);
          lsum += fmaxf(hnv - s + LOSS_MARGIN, 0.f);
          lcnt += 1;
        }
      }
    }
  }

  for (int off = 32; off; off >>= 1) {
    lsum += __shfl_down(lsum, off);
    lcnt += __shfl_down(lcnt, off);
  }
  __shared__ float wsum[4];
  __shared__ int wcnt[4];
  if (lane == 0) { wsum[wave] = lsum; wcnt[wave] = lcnt; }
  __syncthreads();
  if (t == 0) {
    bsum[bid] = wsum[0] + wsum[1] + wsum[2] + wsum[3];
    bcnt[bid] = wcnt[0] + wcnt[1] + wcnt[2] + wcnt[3];
  }
}

// ---- final deterministic reduction -> scalar ----
__global__ __launch_bounds__(256) void finalize_kernel(const float* __restrict__ bsum,
                                                       const int* __restrict__ bcnt,
                                                       float* __restrict__ out) {
  const int t = threadIdx.x;
  float s = bsum[t];
  int n = bcnt[t];
  for (int off = 32; off; off >>= 1) {
    s += __shfl_down(s, off);
    n += __shfl_down(n, off);
  }
  __shared__ float wsum[4];
  __shared__ int wcnt[4];
  if ((t & 63) == 0) { wsum[t >> 6] = s; wcnt[t >> 6] = n; }
  __syncthreads();
  if (t == 0) {
    const float S = wsum[0] + wsum[1] + wsum[2] + wsum[3];
    const int N = wcnt[0] + wcnt[1] + wcnt[2] + wcnt[3];
    out[0] = (N > 0) ? (S / (float)N) : 0.0f;
  }
}

extern "C" void kernel_launch(void* const* d_in, const int* in_sizes, int n_in,
                              void* d_out, int out_size, void* d_ws, size_t ws_size,
                              hipStream_t stream) {
  const float* P = (const float*)d_in[0];
  const int* aff = (const int*)d_in[1];
  const int* inst = (const int*)d_in[2];
  float* out = (float*)d_out;

  unsigned short* Psort = (unsigned short*)d_ws;              // 4 MB
  float* part = (float*)((char*)d_ws + (size_t)NB * ND * 2);  // 2 MB
  unsigned short* simbuf =
      (unsigned short*)((char*)part + (size_t)NT * NB * 4);   // 256*16384*2B = 8 MB
  int* ibase = (int*)((char*)simbuf + (size_t)256 * 16384 * 2);
  float* hn        = (float*)ibase;                           // NB
  int* class_start = ibase + NB;                              // NCLS+1
  int* class_idx   = ibase + NB + NCLS + 1;                   // NB
  int* affSort     = ibase + 2 * NB + NCLS + 1;               // NB
  int* instSort    = ibase + 3 * NB + NCLS + 1;               // NB
  float* bsum = (float*)(ibase + 4 * NB + NCLS + 1);          // NBLK_LOSS
  int* bcnt   = ibase + 4 * NB + NCLS + 1 + NBLK_LOSS;        // NBLK_LOSS

  build_idx<<<NCLS, 256, 0, stream>>>(aff, class_start, class_idx);
  gather_convert<<<NB / 8, 256, 0, stream>>>(P, aff, inst, class_idx, Psort,
                                             affSort, instSort);
  simmax_mfma<<<NTILE_T, 256, 0, stream>>>(Psort, affSort, part, simbuf);
  hn_reduce<<<NB / 256, 256, 0, stream>>>(part, hn);
  loss_pairs<<<dim3(4, NCLS), 256, 0, stream>>>(class_start, instSort, hn,
                                                simbuf, bsum, bcnt);
  finalize_kernel<<<1, 256, 0, stream>>>(bsum, bcnt, out);
}

// Round 16
// 92.785 us; speedup vs baseline: 1.3916x; 1.3916x over previous
//
#include <hip/hip_runtime.h>

#define NB 8192
#define ND 256
#define NCLS 64
#define LOSS_MARGIN 0.2f
#define NEG_INF_F (-1e9f)
#define NT 64           // 8192/128 tile grid
#define NTILE_T 2080    // 64*65/2 triangular tiles

typedef __attribute__((ext_vector_type(8))) __bf16 bf16x8;
typedef __attribute__((ext_vector_type(4))) float f32x4;

// fp32 -> bf16 bits, round-to-nearest-even
__device__ __forceinline__ unsigned short f2bf(float f) {
  unsigned u = __float_as_uint(f);
  unsigned r = (u + 0x7fffu + ((u >> 16) & 1u)) >> 16;
  return (unsigned short)r;
}

// async global->LDS, 16 bytes per lane
__device__ __forceinline__ void gl_lds16(const void* gsrc, void* ldst) {
  __builtin_amdgcn_global_load_lds(
      (const __attribute__((address_space(1))) void*)gsrc,
      (__attribute__((address_space(3))) void*)ldst, 16, 0, 0);
}

// ---- class_start + stable class index list; 2 barriers total ----
__global__ __launch_bounds__(256) void build_idx(const int* __restrict__ aff,
                                                 int* __restrict__ class_start,
                                                 int* __restrict__ class_idx) {
  const int c = blockIdx.x;
  const int t = threadIdx.x;
  const int lane = t & 63, wave = t >> 6;
  __shared__ int wtotLT[4];
  __shared__ int wtotEQ[4];

  int a[32];
#pragma unroll
  for (int k = 0; k < 32; ++k) a[k] = aff[t * 32 + k];
  int ltc = 0, meq = 0;
#pragma unroll
  for (int k = 0; k < 32; ++k) {
    ltc += (a[k] < c) ? 1 : 0;
    meq += (a[k] == c) ? 1 : 0;
  }

  int sc = meq;
  for (int d = 1; d < 64; d <<= 1) {
    int n = __shfl_up(sc, d);
    if (lane >= d) sc += n;
  }
  int ltr = ltc;
  for (int off = 32; off; off >>= 1) ltr += __shfl_down(ltr, off);
  if (lane == 63) wtotEQ[wave] = sc;
  if (lane == 0) wtotLT[wave] = ltr;
  __syncthreads();

  int base = wtotLT[0] + wtotLT[1] + wtotLT[2] + wtotLT[3];
  int wpre = 0;
  for (int w = 0; w < wave; ++w) wpre += wtotEQ[w];
  int p = base + wpre + (sc - meq);

  if (t == 0) {
    class_start[c] = base;
    if (c == 0) class_start[NCLS] = NB;
  }
#pragma unroll
  for (int k = 0; k < 32; ++k)
    if (a[k] == c) class_idx[p++] = t * 32 + k;
}

// ---- gather rows in class order, convert to bf16 (grid-wide parallel) ----
__global__ __launch_bounds__(256) void gather_convert(const float* __restrict__ P,
                                                      const int* __restrict__ aff,
                                                      const int* __restrict__ inst,
                                                      const int* __restrict__ class_idx,
                                                      unsigned short* __restrict__ Psort,
                                                      int* __restrict__ affSort,
                                                      int* __restrict__ instSort) {
  const int t = threadIdx.x;
  const int sr = blockIdx.x * 8 + (t >> 5);
  const int c = t & 31;
  const int src = class_idx[sr];
  const float4* ps = (const float4*)(P + (size_t)src * ND);
  ushort4* pd = (ushort4*)(Psort + (size_t)sr * ND);
#pragma unroll
  for (int q = 0; q < 2; ++q) {
    float4 v = ps[c + q * 32];
    ushort4 h;
    h.x = f2bf(v.x); h.y = f2bf(v.y); h.z = f2bf(v.z); h.w = f2bf(v.w);
    pd[c + q * 32] = h;
  }
  if (c == 0) {
    affSort[sr] = aff[src];
    instSort[sr] = inst[src];
  }
}

// ---- MFMA simmax: R13-exact K-loop; masked tiles also store sims (bf16) ----
// part layout: [tileCol][row]; simbuf slot = bi*4 + (bj-bi), 128x128 bf16.
__global__ __launch_bounds__(256, 4) void simmax_mfma(const unsigned short* __restrict__ Psort,
                                                      const int* __restrict__ affSort,
                                                      float* __restrict__ part,
                                                      unsigned short* __restrict__ simbuf) {
  int wg = blockIdx.x;
  wg = (wg & 7) * (NTILE_T / 8) + (wg >> 3);
  int bi = (int)((129.0f - sqrtf(129.0f * 129.0f - 8.0f * (float)wg)) * 0.5f);
  while (bi * 64 - bi * (bi - 1) / 2 > wg) --bi;
  while ((bi + 1) * 64 - (bi + 1) * bi / 2 <= wg) ++bi;
  const int bj = bi + (wg - (bi * 64 - bi * (bi - 1) / 2));

  __shared__ __align__(16) unsigned short smemu[16384];
  float* rowmax_s = (float*)&smemu[0];     // [128][2], overlays buffer 0 A
  float* colmax_s = (float*)&smemu[512];   // [128][2]

  const int t = threadIdx.x;
  const int lane = t & 63;
  const int wave = t >> 6;
  const int r0 = bi * 128, c0 = bj * 128;

  const bool needMask = (affSort[c0] <= affSort[r0 + 127]);

  const int wr = (wave >> 1) * 64;
  const int wc = (wave & 1) * 64;

  f32x4 acc[4][4];
#pragma unroll
  for (int m = 0; m < 4; ++m)
#pragma unroll
    for (int n = 0; n < 4; ++n) acc[m][n] = (f32x4){0.f, 0.f, 0.f, 0.f};

  const int ci0 = t, ci1 = 256 + t;
  const int kg0 = ci0 >> 7, rw0 = ci0 & 127;
  const int kg1 = ci1 >> 7, rw1 = ci1 & 127;

#define STAGE_SIM(B, KC)                                                      \
  do {                                                                        \
    gl_lds16(Psort + (size_t)(r0 + rw0) * ND + (KC) + kg0 * 8,                \
             &smemu[(B) * 4096 + ci0 * 8]);                                   \
    gl_lds16(Psort + (size_t)(c0 + rw0) * ND + (KC) + kg0 * 8,                \
             &smemu[8192 + (B) * 4096 + ci0 * 8]);                            \
    gl_lds16(Psort + (size_t)(r0 + rw1) * ND + (KC) + kg1 * 8,                \
             &smemu[(B) * 4096 + ci1 * 8]);                                   \
    gl_lds16(Psort + (size_t)(c0 + rw1) * ND + (KC) + kg1 * 8,                \
             &smemu[8192 + (B) * 4096 + ci1 * 8]);                            \
  } while (0)

  STAGE_SIM(0, 0);
  asm volatile("s_waitcnt vmcnt(0) lgkmcnt(0)" ::: "memory");
  __builtin_amdgcn_s_barrier();
  __builtin_amdgcn_sched_barrier(0);

  int cur = 0;
#pragma unroll 1
  for (int s = 0; s < 8; ++s) {
    if (s < 7) STAGE_SIM(cur ^ 1, (s + 1) * 32);
    const int kg = lane >> 4, lr = lane & 15;
    bf16x8 a[4], b[4];
#pragma unroll
    for (int m = 0; m < 4; ++m)
      a[m] = *(const bf16x8*)&smemu[cur * 4096 + (kg * 128 + wr + m * 16 + lr) * 8];
#pragma unroll
    for (int n = 0; n < 4; ++n)
      b[n] = *(const bf16x8*)&smemu[8192 + cur * 4096 + (kg * 128 + wc + n * 16 + lr) * 8];
#pragma unroll
    for (int m = 0; m < 4; ++m)
#pragma unroll
      for (int n = 0; n < 4; ++n)
        acc[m][n] = __builtin_amdgcn_mfma_f32_16x16x32_bf16(a[m], b[n], acc[m][n], 0, 0, 0);
    __builtin_amdgcn_sched_barrier(0);
    if (s < 7) {
      asm volatile("s_waitcnt vmcnt(0)" ::: "memory");
      __builtin_amdgcn_s_barrier();
      __builtin_amdgcn_sched_barrier(0);
    }
    cur ^= 1;
  }
  // all waves past the s==6 barrier: buffer 0 is dead -> reuse as scratch

  if (needMask) {
    int aj[4];
#pragma unroll
    for (int n = 0; n < 4; ++n) aj[n] = affSort[c0 + wc + n * 16 + (lane & 15)];
#pragma unroll
    for (int m = 0; m < 4; ++m) {
#pragma unroll
      for (int r = 0; r < 4; ++r) {
        const int lrow = wr + m * 16 + (lane >> 4) * 4 + r;
        const int ai = affSort[r0 + lrow];
        float rmax = NEG_INF_F;
#pragma unroll
        for (int n = 0; n < 4; ++n)
          if (aj[n] != ai) rmax = fmaxf(rmax, acc[m][n][r]);
        rmax = fmaxf(rmax, __shfl_xor(rmax, 1));
        rmax = fmaxf(rmax, __shfl_xor(rmax, 2));
        rmax = fmaxf(rmax, __shfl_xor(rmax, 4));
        rmax = fmaxf(rmax, __shfl_xor(rmax, 8));
        if ((lane & 15) == 0) rowmax_s[lrow * 2 + (wc >> 6)] = rmax;
      }
    }
    if (bi != bj) {
#pragma unroll
      for (int n = 0; n < 4; ++n) {
        const int lcol = wc + n * 16 + (lane & 15);
        float cmax = NEG_INF_F;
#pragma unroll
        for (int m = 0; m < 4; ++m) {
          const int lrb = wr + m * 16 + (lane >> 4) * 4;
#pragma unroll
          for (int r = 0; r < 4; ++r)
            if (affSort[r0 + lrb + r] != aj[n]) cmax = fmaxf(cmax, acc[m][n][r]);
        }
        cmax = fmaxf(cmax, __shfl_xor(cmax, 16));
        cmax = fmaxf(cmax, __shfl_xor(cmax, 32));
        if (lane < 16) colmax_s[lcol * 2 + (wr >> 6)] = cmax;
      }
    }
    // store the sim tile (bf16) for the loss pass; slot = bi*4 + (bj-bi)
    const int d = bj - bi;
    if (d < 4) {
      unsigned short* dst = simbuf + ((size_t)((bi << 2) + d) << 14);
#pragma unroll
      for (int m = 0; m < 4; ++m) {
#pragma unroll
        for (int r = 0; r < 4; ++r) {
          const int lrow = wr + m * 16 + (lane >> 4) * 4 + r;
#pragma unroll
          for (int n = 0; n < 4; ++n) {
            const int lcol = wc + n * 16 + (lane & 15);
            dst[lrow * 128 + lcol] = f2bf(acc[m][n][r]);
          }
        }
      }
    }
  } else {
#pragma unroll
    for (int m = 0; m < 4; ++m) {
#pragma unroll
      for (int r = 0; r < 4; ++r) {
        float rmax = fmaxf(fmaxf(acc[m][0][r], acc[m][1][r]),
                           fmaxf(acc[m][2][r], acc[m][3][r]));
        rmax = fmaxf(rmax, __shfl_xor(rmax, 1));
        rmax = fmaxf(rmax, __shfl_xor(rmax, 2));
        rmax = fmaxf(rmax, __shfl_xor(rmax, 4));
        rmax = fmaxf(rmax, __shfl_xor(rmax, 8));
        if ((lane & 15) == 0)
          rowmax_s[(wr + m * 16 + (lane >> 4) * 4 + r) * 2 + (wc >> 6)] = rmax;
      }
    }
#pragma unroll
    for (int n = 0; n < 4; ++n) {
      float cmax = NEG_INF_F;
#pragma unroll
      for (int m = 0; m < 4; ++m)
#pragma unroll
        for (int r = 0; r < 4; ++r) cmax = fmaxf(cmax, acc[m][n][r]);
      cmax = fmaxf(cmax, __shfl_xor(cmax, 16));
      cmax = fmaxf(cmax, __shfl_xor(cmax, 32));
      if (lane < 16) colmax_s[(wc + n * 16 + (lane & 15)) * 2 + (wr >> 6)] = cmax;
    }
  }
  __syncthreads();
  if (t < 128) {
    part[(size_t)bj * NB + (r0 + t)] = fmaxf(rowmax_s[t * 2], rowmax_s[t * 2 + 1]);
  } else if (bi != bj) {
    const int cc = t - 128;
    part[(size_t)bi * NB + (c0 + cc)] = fmaxf(colmax_s[cc * 2], colmax_s[cc * 2 + 1]);
  }
#undef STAGE_SIM
}

// ---- reduce 64 partial maxima per row -> hn[row] (coalesced col-major) ----
__global__ __launch_bounds__(256) void hn_reduce(const float* __restrict__ part,
                                                 float* __restrict__ hn) {
  const int i = blockIdx.x * 256 + threadIdx.x;
  float m = NEG_INF_F;
#pragma unroll 16
  for (int q = 0; q < NT; ++q) m = fmaxf(m, part[(size_t)q * NB + i]);
  hn[i] = m;
}

// ---- loss over positive pairs via stored sims; ONE BLOCK PER ANCHOR ----
__global__ __launch_bounds__(256) void loss_pairs(const int* __restrict__ class_start,
                                                  const int* __restrict__ affSort,
                                                  const int* __restrict__ instSort,
                                                  const float* __restrict__ hn,
                                                  const unsigned short* __restrict__ simbuf,
                                                  float* __restrict__ bsum,
                                                  int* __restrict__ bcnt) {
  const int gi = blockIdx.x;           // sorted anchor row
  const int t = threadIdx.x;
  const int lane = t & 63, wave = t >> 6;
  const int c = affSort[gi];
  const int base = class_start[c];
  const int cnt = class_start[c + 1] - base;

  float lsum = 0.f;
  int lcnt = 0;

  if (cnt < NB) {
    const float hnv = hn[gi];
    const int ii = instSort[gi];
    const int ri = gi - base;
#pragma unroll 1
    for (int rj = t; rj < cnt; rj += 256) {
      if (rj == ri) continue;
      const int gj = base + rj;
      if (instSort[gj] != ii) {
        const int lo = min(gi, gj), hi = max(gi, gj);
        const int b0 = lo >> 7, d = (hi >> 7) - b0;
        const unsigned short sb =
            simbuf[((size_t)((b0 << 2) + d) << 14) + ((lo & 127) << 7) + (hi & 127)];
        const float s = __uint_as_float((unsigned)sb << 16);
        lsum += fmaxf(hnv - s + LOSS_MARGIN, 0.f);
        lcnt += 1;
      }
    }
  }

  for (int off = 32; off; off >>= 1) {
    lsum += __shfl_down(lsum, off);
    lcnt += __shfl_down(lcnt, off);
  }
  __shared__ float wsum[4];
  __shared__ int wcnt[4];
  if (lane == 0) { wsum[wave] = lsum; wcnt[wave] = lcnt; }
  __syncthreads();
  if (t == 0) {
    bsum[gi] = wsum[0] + wsum[1] + wsum[2] + wsum[3];
    bcnt[gi] = wcnt[0] + wcnt[1] + wcnt[2] + wcnt[3];
  }
}

// ---- final deterministic reduction -> scalar ----
__global__ __launch_bounds__(256) void finalize_kernel(const float* __restrict__ bsum,
                                                       const int* __restrict__ bcnt,
                                                       float* __restrict__ out) {
  const int t = threadIdx.x;
  float s = 0.f;
  int n = 0;
  for (int i = t; i < NB; i += 256) { s += bsum[i]; n += bcnt[i]; }
  for (int off = 32; off; off >>= 1) {
    s += __shfl_down(s, off);
    n += __shfl_down(n, off);
  }
  __shared__ float wsum[4];
  __shared__ int wcnt[4];
  if ((t & 63) == 0) { wsum[t >> 6] = s; wcnt[t >> 6] = n; }
  __syncthreads();
  if (t == 0) {
    const float S = wsum[0] + wsum[1] + wsum[2] + wsum[3];
    const int N = wcnt[0] + wcnt[1] + wcnt[2] + wcnt[3];
    out[0] = (N > 0) ? (S / (float)N) : 0.0f;
  }
}

extern "C" void kernel_launch(void* const* d_in, const int* in_sizes, int n_in,
                              void* d_out, int out_size, void* d_ws, size_t ws_size,
                              hipStream_t stream) {
  const float* P = (const float*)d_in[0];
  const int* aff = (const int*)d_in[1];
  const int* inst = (const int*)d_in[2];
  float* out = (float*)d_out;

  unsigned short* Psort = (unsigned short*)d_ws;              // 4 MB
  float* part = (float*)((char*)d_ws + (size_t)NB * ND * 2);  // 2 MB
  unsigned short* simbuf =
      (unsigned short*)((char*)part + (size_t)NT * NB * 4);   // 256*16384*2B = 8 MB
  int* ibase = (int*)((char*)simbuf + (size_t)256 * 16384 * 2);
  float* hn        = (float*)ibase;                           // NB
  int* class_start = ibase + NB;                              // NCLS+1
  int* class_idx   = ibase + NB + NCLS + 1;                   // NB
  int* affSort     = ibase + 2 * NB + NCLS + 1;               // NB
  int* instSort    = ibase + 3 * NB + NCLS + 1;               // NB
  float* bsum = (float*)(ibase + 4 * NB + NCLS + 1);          // NB
  int* bcnt   = ibase + 5 * NB + NCLS + 1;                    // NB

  build_idx<<<NCLS, 256, 0, stream>>>(aff, class_start, class_idx);
  gather_convert<<<NB / 8, 256, 0, stream>>>(P, aff, inst, class_idx, Psort,
                                             affSort, instSort);
  simmax_mfma<<<NTILE_T, 256, 0, stream>>>(Psort, affSort, part, simbuf);
  hn_reduce<<<NB / 256, 256, 0, stream>>>(part, hn);
  loss_pairs<<<NB, 256, 0, stream>>>(class_start, affSort, instSort, hn,
                                     simbuf, bsum, bcnt);
  finalize_kernel<<<1, 256, 0, stream>>>(bsum, bcnt, out);
}